// Round 8
// baseline (64.394 us; speedup 1.0000x reference)
//
#include <hip/hip_runtime.h>
#include <math.h>
#include <stdint.h>

#define D_MODEL 512
#define D_STATE 16
#define NSEQ    2048
#define NBATCH  4
#define EPSF    1e-8f
#define LN_EPSF 1e-5f
#define DT      (1.0f / 2048.0f)

typedef __attribute__((ext_vector_type(8))) short short8;
typedef __attribute__((ext_vector_type(4))) float floatx4;

__device__ __forceinline__ ushort f2bf(float f) {
    uint32_t u = __float_as_uint(f);
    return (ushort)((u + 0x7fffu + ((u >> 16) & 1u)) >> 16);
}

// ---------------------------------------------------------------------------
// kP (512 blocks x 256): per block = 16 rows (= one scan chunk).
//  - W_gate f32->bf16 slice (64 thr)
//  - Bu dot: thread (s=lane&15, rloc=(lane>>4)+wave*4) over LDS-staged W_B*B_bar
//  - 16-row LOCAL scan (shfl offsets 16/32 + cross-wave LDS combine)
//  - writes hL[row][s] (unclipped local) + states[chunk][s] (chunk end)
// ---------------------------------------------------------------------------
__global__ __launch_bounds__(256) void kP(const float* __restrict__ x,
                                          const float* __restrict__ A_log,
                                          const float* __restrict__ W_B,
                                          const float* __restrict__ Wg,
                                          ushort* __restrict__ wgb,
                                          float* __restrict__ hL,
                                          float* __restrict__ states) {
    __shared__ float wb[D_STATE][D_MODEL + 4];
    __shared__ float bbars[16], abars[16];
    __shared__ float w4[4][16];
    const int tid = threadIdx.x, lane = tid & 63, wave = tid >> 6;

    if (tid < 64) {                       // W_gate cvt slice
        int i = blockIdx.x * 64 + tid;
        const float4* sp = (const float4*)Wg + (size_t)i * 2;
        float4 a = sp[0], b = sp[1];
        float v[8] = {a.x, a.y, a.z, a.w, b.x, b.y, b.z, b.w};
        short8 o;
        #pragma unroll
        for (int j = 0; j < 8; ++j) o[j] = (short)f2bf(v[j]);
        *(short8*)(wgb + (size_t)i * 8) = o;
    }
    if (tid < 16) {
        float A    = -fminf(fmaxf(expf(A_log[tid]), EPSF), 10.0f);
        float Abar = expf(A * DT);
        abars[tid] = Abar;
        bbars[tid] = (fabsf(A) > EPSF) ? (Abar - 1.0f) / (A + EPSF) : DT;
    }
    __syncthreads();
    for (int i = tid; i < D_STATE * D_MODEL; i += 256) {
        int s = i >> 9, m = i & 511;
        wb[s][m] = W_B[i] * bbars[s];
    }
    __syncthreads();

    const int s    = lane & 15;
    const int q    = lane >> 4;                 // 0..3
    const int rloc = q + (wave << 2);           // 0..15
    const int row  = blockIdx.x * 16 + rloc;
    const float* xr = x + (size_t)row * D_MODEL;

    float acc = 0.f;
    #pragma unroll 4
    for (int m = 0; m < D_MODEL; m += 4) {
        float4 xv = *(const float4*)(xr + m);
        float4 wv = *(const float4*)(&wb[s][m]);
        acc += xv.x * wv.x + xv.y * wv.y + xv.z * wv.z + xv.w * wv.w;
    }

    float abar = abars[s];
    float a = abar, b = acc;
    {
        float ap = __shfl_up(a, 16), bp = __shfl_up(b, 16);
        if (lane >= 16) { b = a * bp + b; a = a * ap; }
    }
    {
        float ap = __shfl_up(a, 32), bp = __shfl_up(b, 32);
        if (lane >= 32) { b = a * bp + b; a = a * ap; }
    }
    if (q == 3) w4[wave][s] = b;
    __syncthreads();
    float a4 = abar * abar; a4 = a4 * a4;       // abar^4
    float pb = 0.f;
    for (int w = 0; w < wave; ++w) pb = a4 * pb + w4[w][s];
    float hloc = a * pb + b;

    hL[(size_t)row * D_STATE + s] = hloc;
    if (rloc == 15) states[(size_t)blockIdx.x * D_STATE + s] = hloc;
}

// ---------------------------------------------------------------------------
// kc (512 blocks x 256): h finalize + gate GEMM (bf16 MFMA, 2-phase LDS
// double-buffer, A direct-from-global in regs) + f32 h@W_C^T + blend + LN.
// ---------------------------------------------------------------------------
#define CBM 16
#define BKC 32
__global__ __launch_bounds__(256) void kc_fused(
    const float*  __restrict__ x,      // (8192,512)
    const ushort* __restrict__ Wg,     // bf16 (512,512)
    const float*  __restrict__ hL,     // (8192,16)
    const float*  __restrict__ states, // (512,16)
    const float*  __restrict__ A_log,
    const float*  __restrict__ W_C,    // (512,16)
    const float*  __restrict__ Dvec,
    const float*  __restrict__ bg,
    const float*  __restrict__ gamma,
    const float*  __restrict__ beta,
    float* __restrict__ out) {
    __shared__ ushort Bsub[2][512 * BKC];   // 2 x 32 KB
    __shared__ float  hsf[CBM][D_STATE];    // 1 KB
    __shared__ float  red[4][CBM][2];       // 512 B

    const int tid  = threadIdx.x;
    const int lane = tid & 63, wave = tid >> 6;
    const int r0   = blockIdx.x * CBM;
    const int fr   = lane & 15, kg = lane >> 4;
    const int colw = wave * 128;

    // ---- chunk-prefix combine -> hsf (f32) ----
    float* stg = (float*)Bsub[1];
    const int c0 = blockIdx.x & 127;
    for (int i = tid; i < c0 * 16; i += 256)
        stg[i] = states[(size_t)(blockIdx.x - c0) * 16 + i];
    __syncthreads();
    {
        int s = tid & 15, nloc = tid >> 4;
        float A   = -fminf(fmaxf(expf(A_log[s]), EPSF), 10.0f);
        float a16 = expf(A * DT * 16.0f);
        float p = 0.f;
        for (int cc = 0; cc < c0; ++cc) p = a16 * p + stg[cc * 16 + s];
        float hv = expf(A * DT * (float)(nloc + 1)) * p
                 + hL[(size_t)(r0 + nloc) * D_STATE + s];
        hsf[nloc][s] = fminf(fmaxf(hv, -10.f), 10.f);
    }
    __syncthreads();   // stg reads done before Bsub[1] reused; hsf visible

    // ---- gate GEMM: 2-phase double-buffered pipeline ----
    const int srow = tid >> 2;        // 0..63
    const int sp   = tid & 3;         // phys 16B slot

    #define STAGE_B(bb, kcc)                                                      \
      { _Pragma("unroll")                                                         \
        for (int is = 0; is < 8; ++is) {                                          \
          int row_ = is * 64 + srow;                                              \
          int g_   = sp ^ (row_ & 3);                                             \
          const ushort* gsrc_ = Wg + (size_t)row_ * D_MODEL + (kcc) + g_ * 8;     \
          __builtin_amdgcn_global_load_lds(                                       \
            (const __attribute__((address_space(1))) void*)gsrc_,                 \
            (__attribute__((address_space(3))) void*)((char*)Bsub[bb] + is * 4096 + tid * 16), \
            16, 0, 0);                                                            \
        } }

    const float* aptr = x + (size_t)(r0 + fr) * D_MODEL + kg * 8;
    float4 av0 = *(const float4*)aptr;
    float4 av1 = *(const float4*)(aptr + 4);
    STAGE_B(0, 0);
    __syncthreads();                  // vmcnt(0): buf0 ready

    floatx4 acc[8] = {};
    int buf = 0;
    for (int t = 0; t < 16; ++t) {
        const int kc = t * BKC;
        float4 nv0 = av0, nv1 = av1;
        if (t < 15) {
            const float* ap = x + (size_t)(r0 + fr) * D_MODEL + kc + BKC + kg * 8;
            nv0 = *(const float4*)ap;
            nv1 = *(const float4*)(ap + 4);
            STAGE_B(buf ^ 1, kc + BKC);      // issue BEFORE compute: flight overlaps MFMA
        }
        short8 af;
        {
            float v[8] = {av0.x,av0.y,av0.z,av0.w,av1.x,av1.y,av1.z,av1.w};
            #pragma unroll
            for (int e = 0; e < 8; ++e) af[e] = (short)f2bf(v[e]);
        }
        #pragma unroll
        for (int j = 0; j < 8; ++j) {
            int rb = colw + j * 16 + fr;
            short8 bv = *(const short8*)(&Bsub[buf][(size_t)rb * BKC + ((kg ^ (rb & 3)) * 8)]);
            acc[j] = __builtin_amdgcn_mfma_f32_16x16x32_bf16(af, bv, acc[j], 0, 0, 0);
        }
        __syncthreads();                     // one barrier/iter: buf^1 ready for next t
        av0 = nv0; av1 = nv1;
        buf ^= 1;
    }

    // ---- epilogue: y = h@W_C^T (f32 VALU) + D*x, blend, LayerNorm ----
    float vsum[4] = {}, vsq[4] = {};
    #pragma unroll
    for (int j = 0; j < 8; ++j) {
        int col = colw + j * 16 + fr;
        float dv = Dvec[col], bgv = bg[col];
        const float4* wcp = (const float4*)(W_C + (size_t)col * D_STATE);
        float4 w0 = wcp[0], w1 = wcp[1], w2 = wcp[2], w3 = wcp[3];
        #pragma unroll
        for (int q = 0; q < 4; ++q) {
            int rl = kg * 4 + q;
            float xv = x[(size_t)(r0 + rl) * D_MODEL + col];
            const float* hp = hsf[rl];
            float yv = dv * xv
                + hp[0]*w0.x + hp[1]*w0.y + hp[2]*w0.z + hp[3]*w0.w
                + hp[4]*w1.x + hp[5]*w1.y + hp[6]*w1.z + hp[7]*w1.w
                + hp[8]*w2.x + hp[9]*w2.y + hp[10]*w2.z + hp[11]*w2.w
                + hp[12]*w3.x + hp[13]*w3.y + hp[14]*w3.z + hp[15]*w3.w;
            float lg = acc[j][q] + bgv;
            float gt = 1.f / (1.f + expf(-lg));
            float v  = gt * yv + (1.f - gt) * xv;
            acc[j][q] = v;
            vsum[q] += v;
            vsq[q]  += v * v;
        }
    }
    #pragma unroll
    for (int off = 1; off < 16; off <<= 1) {
        #pragma unroll
        for (int q = 0; q < 4; ++q) {
            vsum[q] += __shfl_xor(vsum[q], off);
            vsq[q]  += __shfl_xor(vsq[q], off);
        }
    }
    if (fr == 0) {
        #pragma unroll
        for (int q = 0; q < 4; ++q) {
            red[wave][kg * 4 + q][0] = vsum[q];
            red[wave][kg * 4 + q][1] = vsq[q];
        }
    }
    __syncthreads();
    float mu[4], rs[4];
    #pragma unroll
    for (int q = 0; q < 4; ++q) {
        int rl = kg * 4 + q;
        float s = 0.f, ss = 0.f;
        #pragma unroll
        for (int w = 0; w < 4; ++w) { s += red[w][rl][0]; ss += red[w][rl][1]; }
        float m   = s * (1.f / (float)D_MODEL);
        float var = ss * (1.f / (float)D_MODEL) - m * m;
        mu[q] = m;
        rs[q] = rsqrtf(var + LN_EPSF);
    }
    #pragma unroll
    for (int j = 0; j < 8; ++j) {
        int col = colw + j * 16 + fr;
        float ga = gamma[col], be = beta[col];
        #pragma unroll
        for (int q = 0; q < 4; ++q)
            out[(size_t)(r0 + kg * 4 + q) * D_MODEL + col] =
                (acc[j][q] - mu[q]) * rs[q] * ga + be;
    }
}

// ---------------------------------------------------------------------------
extern "C" void kernel_launch(void* const* d_in, const int* in_sizes, int n_in,
                              void* d_out, int out_size, void* d_ws, size_t ws_size,
                              hipStream_t stream) {
    const float* x     = (const float*)d_in[0];
    const float* A_log = (const float*)d_in[1];
    const float* W_B   = (const float*)d_in[2];
    const float* W_C   = (const float*)d_in[3];
    const float* Dv    = (const float*)d_in[4];
    const float* Wg    = (const float*)d_in[5];
    const float* bg    = (const float*)d_in[6];
    const float* gamma = (const float*)d_in[7];
    const float* beta  = (const float*)d_in[8];
    float* out = (float*)d_out;

    const int rows = NBATCH * NSEQ;                            // 8192

    ushort* wgb    = (ushort*)d_ws;                            // 512 KB
    float*  hL     = (float*)(wgb + (size_t)D_MODEL * D_MODEL);// 512 KB
    float*  states = hL + (size_t)rows * D_STATE;              // 32 KB

    hipLaunchKernelGGL(kP, dim3(rows / 16), dim3(256), 0, stream,
                       x, A_log, W_B, Wg, wgb, hL, states);
    hipLaunchKernelGGL(kc_fused, dim3(rows / CBM), dim3(256), 0, stream,
                       x, wgb, hL, states, A_log, W_C, Dv, bg, gamma, beta, out);
}

// Round 9
// 59.884 us; speedup vs baseline: 1.0753x; 1.0753x over previous
//
#include <hip/hip_runtime.h>
#include <math.h>
#include <stdint.h>

#define D_MODEL 512
#define D_STATE 16
#define NSEQ    2048
#define NBATCH  4
#define EPSF    1e-8f
#define LN_EPSF 1e-5f
#define DT      (1.0f / 2048.0f)

typedef __attribute__((ext_vector_type(8))) short short8;
typedef __attribute__((ext_vector_type(4))) float floatx4;

__device__ __forceinline__ ushort f2bf(float f) {
    uint32_t u = __float_as_uint(f);
    return (ushort)((u + 0x7fffu + ((u >> 16) & 1u)) >> 16);
}

// ---------------------------------------------------------------------------
// kP (512 blocks x 256): per block = 16 rows (= one scan chunk).
//  - W_gate f32->bf16 slice (64 thr)
//  - Bu dot over LDS-staged W_B*B_bar
//  - 16-row LOCAL scan -> hL[row][s], chunk end -> states[chunk][s]
// ---------------------------------------------------------------------------
__global__ __launch_bounds__(256) void kP(const float* __restrict__ x,
                                          const float* __restrict__ A_log,
                                          const float* __restrict__ W_B,
                                          const float* __restrict__ Wg,
                                          ushort* __restrict__ wgb,
                                          float* __restrict__ hL,
                                          float* __restrict__ states) {
    __shared__ float wb[D_STATE][D_MODEL + 4];
    __shared__ float bbars[16], abars[16];
    __shared__ float w4[4][16];
    const int tid = threadIdx.x, lane = tid & 63, wave = tid >> 6;

    if (tid < 64) {                       // W_gate cvt slice
        int i = blockIdx.x * 64 + tid;
        const float4* sp = (const float4*)Wg + (size_t)i * 2;
        float4 a = sp[0], b = sp[1];
        float v[8] = {a.x, a.y, a.z, a.w, b.x, b.y, b.z, b.w};
        short8 o;
        #pragma unroll
        for (int j = 0; j < 8; ++j) o[j] = (short)f2bf(v[j]);
        *(short8*)(wgb + (size_t)i * 8) = o;
    }
    if (tid < 16) {
        float A    = -fminf(fmaxf(expf(A_log[tid]), EPSF), 10.0f);
        float Abar = expf(A * DT);
        abars[tid] = Abar;
        bbars[tid] = (fabsf(A) > EPSF) ? (Abar - 1.0f) / (A + EPSF) : DT;
    }
    __syncthreads();
    for (int i = tid; i < D_STATE * D_MODEL; i += 256) {
        int s = i >> 9, m = i & 511;
        wb[s][m] = W_B[i] * bbars[s];
    }
    __syncthreads();

    const int s    = lane & 15;
    const int q    = lane >> 4;
    const int rloc = q + (wave << 2);
    const int row  = blockIdx.x * 16 + rloc;
    const float* xr = x + (size_t)row * D_MODEL;

    float acc = 0.f;
    #pragma unroll 4
    for (int m = 0; m < D_MODEL; m += 4) {
        float4 xv = *(const float4*)(xr + m);
        float4 wv = *(const float4*)(&wb[s][m]);
        acc += xv.x * wv.x + xv.y * wv.y + xv.z * wv.z + xv.w * wv.w;
    }

    float abar = abars[s];
    float a = abar, b = acc;
    {
        float ap = __shfl_up(a, 16), bp = __shfl_up(b, 16);
        if (lane >= 16) { b = a * bp + b; a = a * ap; }
    }
    {
        float ap = __shfl_up(a, 32), bp = __shfl_up(b, 32);
        if (lane >= 32) { b = a * bp + b; a = a * ap; }
    }
    if (q == 3) w4[wave][s] = b;
    __syncthreads();
    float a4 = abar * abar; a4 = a4 * a4;
    float pb = 0.f;
    for (int w = 0; w < wave; ++w) pb = a4 * pb + w4[w][s];
    float hloc = a * pb + b;

    hL[(size_t)row * D_STATE + s] = hloc;
    if (rloc == 15) states[(size_t)blockIdx.x * D_STATE + s] = hloc;
}

// ---------------------------------------------------------------------------
// kc (512 blocks x 256): h finalize + gate GEMM with COUNTED-vmcnt pipeline
// (raw s_barrier, stage flight spans barriers) + f32 h@W_C^T + blend + LN.
// ---------------------------------------------------------------------------
#define CBM 16
#define BKC 32
__global__ __launch_bounds__(256) void kc_fused(
    const float*  __restrict__ x,      // (8192,512)
    const ushort* __restrict__ Wg,     // bf16 (512,512)
    const float*  __restrict__ hL,     // (8192,16)
    const float*  __restrict__ states, // (512,16)
    const float*  __restrict__ A_log,
    const float*  __restrict__ W_C,    // (512,16)
    const float*  __restrict__ Dvec,
    const float*  __restrict__ bg,
    const float*  __restrict__ gamma,
    const float*  __restrict__ beta,
    float* __restrict__ out) {
    __shared__ ushort Bsub[2][512 * BKC];   // 2 x 32 KB
    __shared__ float  hsf[CBM][D_STATE];    // 1 KB
    __shared__ float  red[4][CBM][2];       // 512 B

    const int tid  = threadIdx.x;
    const int lane = tid & 63, wave = tid >> 6;
    const int r0   = blockIdx.x * CBM;
    const int fr   = lane & 15, kg = lane >> 4;
    const int colw = wave * 128;

    // ---- chunk-prefix combine -> hsf (f32) ----
    float* stg = (float*)Bsub[1];
    const int c0 = blockIdx.x & 127;
    for (int i = tid; i < c0 * 16; i += 256)
        stg[i] = states[(size_t)(blockIdx.x - c0) * 16 + i];
    __syncthreads();
    {
        int s = tid & 15, nloc = tid >> 4;
        float A   = -fminf(fmaxf(expf(A_log[s]), EPSF), 10.0f);
        float a16 = expf(A * DT * 16.0f);
        float p = 0.f;
        for (int cc = 0; cc < c0; ++cc) p = a16 * p + stg[cc * 16 + s];
        float hv = expf(A * DT * (float)(nloc + 1)) * p
                 + hL[(size_t)(r0 + nloc) * D_STATE + s];
        hsf[nloc][s] = fminf(fmaxf(hv, -10.f), 10.f);
    }
    __syncthreads();   // stg reads done before Bsub[1] staged; hsf visible

    // ---- gate GEMM: counted-vmcnt double-buffered pipeline ----
    const int srow = tid >> 2;        // 0..63
    const int sp   = tid & 3;         // phys 16B slot

    #define STAGE_B(bb, kcc)                                                      \
      { _Pragma("unroll")                                                         \
        for (int is = 0; is < 8; ++is) {                                          \
          int row_ = is * 64 + srow;                                              \
          int g_   = sp ^ (row_ & 3);                                             \
          const ushort* gsrc_ = Wg + (size_t)row_ * D_MODEL + (kcc) + g_ * 8;     \
          __builtin_amdgcn_global_load_lds(                                       \
            (const __attribute__((address_space(1))) void*)gsrc_,                 \
            (__attribute__((address_space(3))) void*)((char*)Bsub[bb] + is * 4096 + tid * 16), \
            16, 0, 0);                                                            \
        } }

    const float* aptr = x + (size_t)(r0 + fr) * D_MODEL + kg * 8;
    float4 av0 = *(const float4*)aptr;
    float4 av1 = *(const float4*)(aptr + 4);
    STAGE_B(0, 0);                    // iter-0 flight (10 ops/wave incl. A)

    floatx4 acc[8] = {};
    #pragma unroll
    for (int t = 0; t < 16; ++t) {
        const int cur = t & 1;
        float4 nv0 = av0, nv1 = av1;
        if (t < 15) {
            const float* ap = x + (size_t)(r0 + fr) * D_MODEL + (t + 1) * BKC + kg * 8;
            nv0 = *(const float4*)ap;          // A(t+1), issued before STAGE(t+1)
            nv1 = *(const float4*)(ap + 4);
            STAGE_B(cur ^ 1, (t + 1) * BKC);   // flight spans the barrier
        }
        __builtin_amdgcn_sched_barrier(0);
        if (t < 15) {
            asm volatile("s_waitcnt vmcnt(10)" ::: "memory");  // iter-t ops done; t+1 in flight
        } else {
            asm volatile("s_waitcnt vmcnt(0)" ::: "memory");
        }
        __builtin_amdgcn_sched_barrier(0);
        __builtin_amdgcn_s_barrier();          // raw: no implicit drain

        short8 af;
        {
            float v[8] = {av0.x,av0.y,av0.z,av0.w,av1.x,av1.y,av1.z,av1.w};
            #pragma unroll
            for (int e = 0; e < 8; ++e) af[e] = (short)f2bf(v[e]);
        }
        #pragma unroll
        for (int j = 0; j < 8; ++j) {
            int rb = colw + j * 16 + fr;
            short8 bv = *(const short8*)(&Bsub[cur][(size_t)rb * BKC + ((kg ^ (rb & 3)) * 8)]);
            acc[j] = __builtin_amdgcn_mfma_f32_16x16x32_bf16(af, bv, acc[j], 0, 0, 0);
        }
        __builtin_amdgcn_s_barrier();          // all waves done reading buf[cur]
        av0 = nv0; av1 = nv1;
    }

    // ---- epilogue: y = h@W_C^T (f32 VALU) + D*x, blend, LayerNorm ----
    float vsum[4] = {}, vsq[4] = {};
    #pragma unroll
    for (int j = 0; j < 8; ++j) {
        int col = colw + j * 16 + fr;
        float dv = Dvec[col], bgv = bg[col];
        const float4* wcp = (const float4*)(W_C + (size_t)col * D_STATE);
        float4 w0 = wcp[0], w1 = wcp[1], w2 = wcp[2], w3 = wcp[3];
        #pragma unroll
        for (int q = 0; q < 4; ++q) {
            int rl = kg * 4 + q;
            float xv = x[(size_t)(r0 + rl) * D_MODEL + col];
            const float* hp = hsf[rl];
            float yv = dv * xv
                + hp[0]*w0.x + hp[1]*w0.y + hp[2]*w0.z + hp[3]*w0.w
                + hp[4]*w1.x + hp[5]*w1.y + hp[6]*w1.z + hp[7]*w1.w
                + hp[8]*w2.x + hp[9]*w2.y + hp[10]*w2.z + hp[11]*w2.w
                + hp[12]*w3.x + hp[13]*w3.y + hp[14]*w3.z + hp[15]*w3.w;
            float lg = acc[j][q] + bgv;
            float gt = 1.f / (1.f + expf(-lg));
            float v  = gt * yv + (1.f - gt) * xv;
            acc[j][q] = v;
            vsum[q] += v;
            vsq[q]  += v * v;
        }
    }
    #pragma unroll
    for (int off = 1; off < 16; off <<= 1) {
        #pragma unroll
        for (int q = 0; q < 4; ++q) {
            vsum[q] += __shfl_xor(vsum[q], off);
            vsq[q]  += __shfl_xor(vsq[q], off);
        }
    }
    if (fr == 0) {
        #pragma unroll
        for (int q = 0; q < 4; ++q) {
            red[wave][kg * 4 + q][0] = vsum[q];
            red[wave][kg * 4 + q][1] = vsq[q];
        }
    }
    __syncthreads();
    float mu[4], rs[4];
    #pragma unroll
    for (int q = 0; q < 4; ++q) {
        int rl = kg * 4 + q;
        float s = 0.f, ss = 0.f;
        #pragma unroll
        for (int w = 0; w < 4; ++w) { s += red[w][rl][0]; ss += red[w][rl][1]; }
        float m   = s * (1.f / (float)D_MODEL);
        float var = ss * (1.f / (float)D_MODEL) - m * m;
        mu[q] = m;
        rs[q] = rsqrtf(var + LN_EPSF);
    }
    #pragma unroll
    for (int j = 0; j < 8; ++j) {
        int col = colw + j * 16 + fr;
        float ga = gamma[col], be = beta[col];
        #pragma unroll
        for (int q = 0; q < 4; ++q)
            out[(size_t)(r0 + kg * 4 + q) * D_MODEL + col] =
                (acc[j][q] - mu[q]) * rs[q] * ga + be;
    }
}

// ---------------------------------------------------------------------------
extern "C" void kernel_launch(void* const* d_in, const int* in_sizes, int n_in,
                              void* d_out, int out_size, void* d_ws, size_t ws_size,
                              hipStream_t stream) {
    const float* x     = (const float*)d_in[0];
    const float* A_log = (const float*)d_in[1];
    const float* W_B   = (const float*)d_in[2];
    const float* W_C   = (const float*)d_in[3];
    const float* Dv    = (const float*)d_in[4];
    const float* Wg    = (const float*)d_in[5];
    const float* bg    = (const float*)d_in[6];
    const float* gamma = (const float*)d_in[7];
    const float* beta  = (const float*)d_in[8];
    float* out = (float*)d_out;

    const int rows = NBATCH * NSEQ;                            // 8192

    ushort* wgb    = (ushort*)d_ws;                            // 512 KB
    float*  hL     = (float*)(wgb + (size_t)D_MODEL * D_MODEL);// 512 KB
    float*  states = hL + (size_t)rows * D_STATE;              // 32 KB

    hipLaunchKernelGGL(kP, dim3(rows / 16), dim3(256), 0, stream,
                       x, A_log, W_B, Wg, wgb, hL, states);
    hipLaunchKernelGGL(kc_fused, dim3(rows / CBM), dim3(256), 0, stream,
                       x, wgb, hL, states, A_log, W_C, Dv, bg, gamma, beta, out);
}